// Round 1
// baseline (3488.165 us; speedup 1.0000x reference)
//
#include <hip/hip_runtime.h>

#define N_NODES   100000
#define N_EDGES   1200000
#define D         64
#define N_GRAPHS  128
#define N_CLASSES 3

// ---------------------------------------------------------------- zero buffer
__global__ void zero_kernel(float* __restrict__ p, int n4) {
    int i = blockIdx.x * blockDim.x + threadIdx.x;
    if (i < n4) ((float4*)p)[i] = make_float4(0.f, 0.f, 0.f, 0.f);
}

// ------------------------------------------------------- edge scatter-add
// 16 threads per edge; each thread moves one float4 (4 feats) with 4 atomics.
__global__ __launch_bounds__(256) void scatter_add_kernel(
        const float* __restrict__ h,
        const int* __restrict__ src,
        const int* __restrict__ dst,
        float* __restrict__ agg) {
    int t  = blockIdx.x * blockDim.x + threadIdx.x;
    int e  = t >> 4;
    if (e >= N_EDGES) return;
    int f4 = (t & 15) << 2;
    int s = src[e];
    int d = dst[e];
    float4 v = *(const float4*)(h + s * D + f4);
    float* p = agg + d * D + f4;
    atomicAdd(p + 0, v.x);
    atomicAdd(p + 1, v.y);
    atomicAdd(p + 2, v.z);
    atomicAdd(p + 3, v.w);
}

// ------------------------------------------- node update: relu(agg@Wr+br+x@Ws)
// 4 nodes per 256-thread block; weights staged in LDS; writes agg in place
// (each block touches only its own 4 rows -> in-place is race-free).
__global__ __launch_bounds__(256) void node_update_kernel(
        float* __restrict__ agg,          // in: aggregate, out: new h (in place)
        const float* __restrict__ xin,    // previous layer features
        const float* __restrict__ Wr,     // [64,64] row-major (fan_in x fan_out)
        const float* __restrict__ br,     // [64]
        const float* __restrict__ Ws) {   // [64,64]
    __shared__ float WrS[D * D];
    __shared__ float WsS[D * D];
    __shared__ float rowA[4][D];
    __shared__ float rowX[4][D];

    for (int i = threadIdx.x; i < D * D; i += 256) {
        WrS[i] = Wr[i];
        WsS[i] = Ws[i];
    }
    int ln = threadIdx.x >> 6;   // local node 0..3
    int f  = threadIdx.x & 63;   // output feature
    int n  = blockIdx.x * 4 + ln;
    if (n < N_NODES) {
        rowA[ln][f] = agg[n * D + f];
        rowX[ln][f] = xin[n * D + f];
    }
    __syncthreads();
    if (n >= N_NODES) return;

    float acc = br[f];
#pragma unroll
    for (int k = 0; k < D; ++k) {
        acc += rowA[ln][k] * WrS[k * D + f] + rowX[ln][k] * WsS[k * D + f];
    }
    agg[n * D + f] = fmaxf(acc, 0.0f);
}

// ------------------------------------------------- pool: segment_sum by batch
// batch[] is sorted. One 64-thread block per 64-node chunk; run-length
// accumulate, one atomic per (chunk, distinct batch id, feature).
__global__ __launch_bounds__(64) void pool_kernel(
        const float* __restrict__ h,
        const int* __restrict__ batch,
        float* __restrict__ g) {
    int n0 = blockIdx.x * 64;
    int f  = threadIdx.x;
    if (n0 >= N_NODES) return;
    float acc = 0.f;
    int cur = batch[n0];
    int nend = n0 + 64;
    if (nend > N_NODES) nend = N_NODES;
    for (int n = n0; n < nend; ++n) {
        int b = batch[n];
        if (b != cur) {
            atomicAdd(&g[cur * D + f], acc);
            acc = 0.f;
            cur = b;
        }
        acc += h[n * D + f];
    }
    atomicAdd(&g[cur * D + f], acc);
}

// ------------------------------------------------------------------- MLP head
// one block per graph: fc1(64->64)+relu, fc2(64->3), log_softmax
__global__ __launch_bounds__(64) void head_kernel(
        const float* __restrict__ g,
        const float* __restrict__ Wfc1, const float* __restrict__ bfc1,
        const float* __restrict__ Wfc2, const float* __restrict__ bfc2,
        float* __restrict__ out) {
    __shared__ float hS[D];
    __shared__ float lS[N_CLASSES];
    int gr = blockIdx.x;
    int f  = threadIdx.x;

    float acc = bfc1[f];
#pragma unroll
    for (int k = 0; k < D; ++k) acc += g[gr * D + k] * Wfc1[k * D + f];
    hS[f] = fmaxf(acc, 0.f);
    __syncthreads();

    if (f < N_CLASSES) {
        float a = bfc2[f];
#pragma unroll
        for (int k = 0; k < D; ++k) a += hS[k] * Wfc2[k * N_CLASSES + f];
        lS[f] = a;
    }
    __syncthreads();

    if (f == 0) {
        float m = fmaxf(lS[0], fmaxf(lS[1], lS[2]));
        float s = expf(lS[0] - m) + expf(lS[1] - m) + expf(lS[2] - m);
        float lse = m + logf(s);
        out[gr * 3 + 0] = lS[0] - lse;
        out[gr * 3 + 1] = lS[1] - lse;
        out[gr * 3 + 2] = lS[2] - lse;
    }
}

// ---------------------------------------------------------------------- launch
extern "C" void kernel_launch(void* const* d_in, const int* in_sizes, int n_in,
                              void* d_out, int out_size, void* d_ws, size_t ws_size,
                              hipStream_t stream) {
    const float* x     = (const float*)d_in[0];
    const int*   edge  = (const int*)d_in[1];
    const int*   batch = (const int*)d_in[2];
    const float* Wr1 = (const float*)d_in[3];
    const float* br1 = (const float*)d_in[4];
    const float* Ws1 = (const float*)d_in[5];
    const float* Wr2 = (const float*)d_in[6];
    const float* br2 = (const float*)d_in[7];
    const float* Ws2 = (const float*)d_in[8];
    const float* Wr3 = (const float*)d_in[9];
    const float* br3 = (const float*)d_in[10];
    const float* Ws3 = (const float*)d_in[11];
    const float* Wfc1 = (const float*)d_in[12];
    const float* bfc1 = (const float*)d_in[13];
    const float* Wfc2 = (const float*)d_in[14];
    const float* bfc2 = (const float*)d_in[15];

    const int* src = edge;
    const int* dst = edge + N_EDGES;

    // workspace: two node-feature buffers (A,B) + pooled graph buffer
    float* A = (float*)d_ws;                     // N_NODES*D
    float* B = A + (size_t)N_NODES * D;          // N_NODES*D
    float* g = B + (size_t)N_NODES * D;          // N_GRAPHS*D

    const int nodeFloats = N_NODES * D;          // 6.4M
    const int n4         = nodeFloats / 4;
    dim3 blkZ(256), grdZ((n4 + 255) / 256);
    dim3 blkS(256), grdS((N_EDGES * 16 + 255) / 256);
    dim3 blkU(256), grdU((N_NODES + 3) / 4);

    // ---- layer 1: A = relu(scatter(x) @ Wr1 + br1 + x @ Ws1)
    zero_kernel<<<grdZ, blkZ, 0, stream>>>(A, n4);
    scatter_add_kernel<<<grdS, blkS, 0, stream>>>(x, src, dst, A);
    node_update_kernel<<<grdU, blkU, 0, stream>>>(A, x, Wr1, br1, Ws1);

    // ---- layer 2: B = relu(scatter(A) @ Wr2 + br2 + A @ Ws2)
    zero_kernel<<<grdZ, blkZ, 0, stream>>>(B, n4);
    scatter_add_kernel<<<grdS, blkS, 0, stream>>>(A, src, dst, B);
    node_update_kernel<<<grdU, blkU, 0, stream>>>(B, A, Wr2, br2, Ws2);

    // ---- layer 3: A = relu(scatter(B) @ Wr3 + br3 + B @ Ws3)
    zero_kernel<<<grdZ, blkZ, 0, stream>>>(A, n4);
    scatter_add_kernel<<<grdS, blkS, 0, stream>>>(B, src, dst, A);
    node_update_kernel<<<grdU, blkU, 0, stream>>>(A, B, Wr3, br3, Ws3);

    // ---- pool + head
    zero_kernel<<<dim3((N_GRAPHS * D / 4 + 255) / 256), blkZ, 0, stream>>>(g, N_GRAPHS * D / 4);
    pool_kernel<<<dim3((N_NODES + 63) / 64), dim3(64), 0, stream>>>(A, batch, g);
    head_kernel<<<dim3(N_GRAPHS), dim3(64), 0, stream>>>(g, Wfc1, bfc1, Wfc2, bfc2, (float*)d_out);
}

// Round 2
// 778.344 us; speedup vs baseline: 4.4815x; 4.4815x over previous
//
#include <hip/hip_runtime.h>

#define N_NODES   100000
#define N_EDGES   1200000
#define D         64
#define N_GRAPHS  128
#define N_CLASSES 3

#define TILE      64          // nodes per block in fused layer
#define LSTRIDE   68          // 64 + 4 pad: keeps float4 alignment, 2-way banks max

// ---------------------------------------------------------------- zero buffer
__global__ void zero_kernel(float* __restrict__ p, int n4) {
    int i = blockIdx.x * blockDim.x + threadIdx.x;
    if (i < n4) ((float4*)p)[i] = make_float4(0.f, 0.f, 0.f, 0.f);
}

// -------------------------------------------------------------- CSR build: deg
__global__ __launch_bounds__(256) void hist_kernel(
        const int* __restrict__ dst, int* __restrict__ deg) {
    int e = blockIdx.x * blockDim.x + threadIdx.x;
    if (e < N_EDGES) atomicAdd(&deg[dst[e]], 1);
}

// --------------------------------------------- CSR build: scan (single block)
__global__ __launch_bounds__(1024) void scan_kernel(
        const int* __restrict__ deg,
        int* __restrict__ row_ptr, int* __restrict__ cursor) {
    __shared__ int sums[1024];
    const int SEG = (N_NODES + 1023) / 1024;   // 98
    int t = threadIdx.x;
    int beg = t * SEG;
    int end = beg + SEG; if (end > N_NODES) end = N_NODES;
    int s = 0;
    for (int i = beg; i < end; ++i) s += deg[i];
    sums[t] = s;
    __syncthreads();
    // Hillis-Steele inclusive scan over 1024 partials
    for (int d = 1; d < 1024; d <<= 1) {
        int v = (t >= d) ? sums[t - d] : 0;
        __syncthreads();
        sums[t] += v;
        __syncthreads();
    }
    int off = sums[t] - s;                     // exclusive prefix
    for (int i = beg; i < end; ++i) {
        row_ptr[i] = off;
        cursor[i]  = off;
        off += deg[i];
    }
    if (t == 0) row_ptr[N_NODES] = N_EDGES;
}

// -------------------------------------------------------------- CSR build: fill
__global__ __launch_bounds__(256) void fill_kernel(
        const int* __restrict__ src, const int* __restrict__ dst,
        int* __restrict__ cursor, int* __restrict__ csr) {
    int e = blockIdx.x * blockDim.x + threadIdx.x;
    if (e < N_EDGES) {
        int p = atomicAdd(&cursor[dst[e]], 1);
        csr[p] = src[e];
    }
}

// --------------------------- fused layer: gather + agg@Wr + h@Ws + br, relu
// Block = 256 threads, 64-node tile. Weights + agg/x rows staged in LDS.
__global__ __launch_bounds__(256) void fused_layer_kernel(
        const float* __restrict__ hin,
        const int* __restrict__ row_ptr,
        const int* __restrict__ csr,
        const float* __restrict__ Wr,
        const float* __restrict__ br,
        const float* __restrict__ Ws,
        float* __restrict__ hout) {
    __shared__ float WrS[D * D];
    __shared__ float WsS[D * D];
    __shared__ float aggS[TILE * LSTRIDE];
    __shared__ float xS[TILE * LSTRIDE];

    int tid = threadIdx.x;
    for (int i = tid; i < D * D; i += 256) {
        WrS[i] = Wr[i];
        WsS[i] = Ws[i];
    }

    const int f4    = (tid & 15) * 4;     // feature quad base
    const int node0 = blockIdx.x * TILE;

    // ---- gather + x staging: 4 rounds x 16 nodes (thread = (node, f4-slice))
    for (int r = 0; r < 4; ++r) {
        int ln = r * 16 + (tid >> 4);
        int n  = node0 + ln;
        float ax = 0.f, ay = 0.f, az = 0.f, aw = 0.f;
        float bx = 0.f, by = 0.f, bz = 0.f, bw = 0.f;
        float cx = 0.f, cy = 0.f, cz = 0.f, cw = 0.f;
        float dx = 0.f, dy = 0.f, dz = 0.f, dw = 0.f;
        if (n < N_NODES) {
            float4 xv = *(const float4*)(hin + (size_t)n * D + f4);
            *(float4*)&xS[ln * LSTRIDE + f4] = xv;
            int beg = row_ptr[n];
            int end = row_ptr[n + 1];
            int j = beg;
            for (; j + 4 <= end; j += 4) {
                int s0 = csr[j + 0], s1 = csr[j + 1];
                int s2 = csr[j + 2], s3 = csr[j + 3];
                float4 v0 = *(const float4*)(hin + (size_t)s0 * D + f4);
                float4 v1 = *(const float4*)(hin + (size_t)s1 * D + f4);
                float4 v2 = *(const float4*)(hin + (size_t)s2 * D + f4);
                float4 v3 = *(const float4*)(hin + (size_t)s3 * D + f4);
                ax += v0.x; ay += v0.y; az += v0.z; aw += v0.w;
                bx += v1.x; by += v1.y; bz += v1.z; bw += v1.w;
                cx += v2.x; cy += v2.y; cz += v2.z; cw += v2.w;
                dx += v3.x; dy += v3.y; dz += v3.z; dw += v3.w;
            }
            for (; j < end; ++j) {
                float4 v = *(const float4*)(hin + (size_t)csr[j] * D + f4);
                ax += v.x; ay += v.y; az += v.z; aw += v.w;
            }
        } else {
            *(float4*)&xS[ln * LSTRIDE + f4] = make_float4(0.f, 0.f, 0.f, 0.f);
        }
        float4 acc = make_float4(ax + bx + cx + dx, ay + by + cy + dy,
                                 az + bz + cz + dz, aw + bw + cw + dw);
        *(float4*)&aggS[ln * LSTRIDE + f4] = acc;
    }
    __syncthreads();

    // ---- GEMM: thread = (node-quad q, feature-quad f4); 4 nodes x 4 feats
    const int q = tid >> 4;               // 0..15 -> nodes 4q..4q+3
    float4 bias = *(const float4*)(br + f4);
    float4 c0 = bias, c1 = bias, c2 = bias, c3 = bias;

#pragma unroll 4
    for (int k = 0; k < D; ++k) {
        float4 wr = *(const float4*)&WrS[k * D + f4];
        float4 ws = *(const float4*)&WsS[k * D + f4];
        float a0 = aggS[(4 * q + 0) * LSTRIDE + k];
        float a1 = aggS[(4 * q + 1) * LSTRIDE + k];
        float a2 = aggS[(4 * q + 2) * LSTRIDE + k];
        float a3 = aggS[(4 * q + 3) * LSTRIDE + k];
        float x0 = xS[(4 * q + 0) * LSTRIDE + k];
        float x1 = xS[(4 * q + 1) * LSTRIDE + k];
        float x2 = xS[(4 * q + 2) * LSTRIDE + k];
        float x3 = xS[(4 * q + 3) * LSTRIDE + k];
        c0.x += a0 * wr.x + x0 * ws.x;  c0.y += a0 * wr.y + x0 * ws.y;
        c0.z += a0 * wr.z + x0 * ws.z;  c0.w += a0 * wr.w + x0 * ws.w;
        c1.x += a1 * wr.x + x1 * ws.x;  c1.y += a1 * wr.y + x1 * ws.y;
        c1.z += a1 * wr.z + x1 * ws.z;  c1.w += a1 * wr.w + x1 * ws.w;
        c2.x += a2 * wr.x + x2 * ws.x;  c2.y += a2 * wr.y + x2 * ws.y;
        c2.z += a2 * wr.z + x2 * ws.z;  c2.w += a2 * wr.w + x2 * ws.w;
        c3.x += a3 * wr.x + x3 * ws.x;  c3.y += a3 * wr.y + x3 * ws.y;
        c3.z += a3 * wr.z + x3 * ws.z;  c3.w += a3 * wr.w + x3 * ws.w;
    }

    float4 cc[4] = {c0, c1, c2, c3};
#pragma unroll
    for (int i = 0; i < 4; ++i) {
        int n = node0 + 4 * q + i;
        if (n < N_NODES) {
            float4 o;
            o.x = fmaxf(cc[i].x, 0.f); o.y = fmaxf(cc[i].y, 0.f);
            o.z = fmaxf(cc[i].z, 0.f); o.w = fmaxf(cc[i].w, 0.f);
            *(float4*)(hout + (size_t)n * D + f4) = o;
        }
    }
}

// ------------------------------------------------- pool: segment_sum by batch
__global__ __launch_bounds__(64) void pool_kernel(
        const float* __restrict__ h,
        const int* __restrict__ batch,
        float* __restrict__ g) {
    int n0 = blockIdx.x * 64;
    int f  = threadIdx.x;
    if (n0 >= N_NODES) return;
    float acc = 0.f;
    int cur = batch[n0];
    int nend = n0 + 64;
    if (nend > N_NODES) nend = N_NODES;
    for (int n = n0; n < nend; ++n) {
        int b = batch[n];
        if (b != cur) {
            atomicAdd(&g[cur * D + f], acc);
            acc = 0.f;
            cur = b;
        }
        acc += h[(size_t)n * D + f];
    }
    atomicAdd(&g[cur * D + f], acc);
}

// ------------------------------------------------------------------- MLP head
__global__ __launch_bounds__(64) void head_kernel(
        const float* __restrict__ g,
        const float* __restrict__ Wfc1, const float* __restrict__ bfc1,
        const float* __restrict__ Wfc2, const float* __restrict__ bfc2,
        float* __restrict__ out) {
    __shared__ float hS[D];
    __shared__ float lS[N_CLASSES];
    int gr = blockIdx.x;
    int f  = threadIdx.x;

    float acc = bfc1[f];
#pragma unroll
    for (int k = 0; k < D; ++k) acc += g[gr * D + k] * Wfc1[k * D + f];
    hS[f] = fmaxf(acc, 0.f);
    __syncthreads();

    if (f < N_CLASSES) {
        float a = bfc2[f];
#pragma unroll
        for (int k = 0; k < D; ++k) a += hS[k] * Wfc2[k * N_CLASSES + f];
        lS[f] = a;
    }
    __syncthreads();

    if (f == 0) {
        float m = fmaxf(lS[0], fmaxf(lS[1], lS[2]));
        float s = expf(lS[0] - m) + expf(lS[1] - m) + expf(lS[2] - m);
        float lse = m + logf(s);
        out[gr * 3 + 0] = lS[0] - lse;
        out[gr * 3 + 1] = lS[1] - lse;
        out[gr * 3 + 2] = lS[2] - lse;
    }
}

// ---------------------------------------------------------------------- launch
extern "C" void kernel_launch(void* const* d_in, const int* in_sizes, int n_in,
                              void* d_out, int out_size, void* d_ws, size_t ws_size,
                              hipStream_t stream) {
    const float* x     = (const float*)d_in[0];
    const int*   edge  = (const int*)d_in[1];
    const int*   batch = (const int*)d_in[2];
    const float* Wr1 = (const float*)d_in[3];
    const float* br1 = (const float*)d_in[4];
    const float* Ws1 = (const float*)d_in[5];
    const float* Wr2 = (const float*)d_in[6];
    const float* br2 = (const float*)d_in[7];
    const float* Ws2 = (const float*)d_in[8];
    const float* Wr3 = (const float*)d_in[9];
    const float* br3 = (const float*)d_in[10];
    const float* Ws3 = (const float*)d_in[11];
    const float* Wfc1 = (const float*)d_in[12];
    const float* bfc1 = (const float*)d_in[13];
    const float* Wfc2 = (const float*)d_in[14];
    const float* bfc2 = (const float*)d_in[15];

    const int* src = edge;
    const int* dst = edge + N_EDGES;

    // workspace layout (all 4B elements; float4 alignment holds throughout)
    float* A       = (float*)d_ws;                        // 6,400,000 f
    float* B       = A + (size_t)N_NODES * D;             // 6,400,000 f
    float* g       = B + (size_t)N_NODES * D;             //     8,192 f
    int*   deg     = (int*)(g + (size_t)N_GRAPHS * D);    //   100,000 i
    int*   row_ptr = deg + N_NODES;                       //   100,001 i
    int*   cursor  = row_ptr + (N_NODES + 1);             //   100,000 i
    int*   csr     = cursor + N_NODES;                    // 1,200,000 i
    // total ~57.2 MB

    dim3 blk256(256);
    dim3 grdE((N_EDGES + 255) / 256);                     // 4688 blocks
    dim3 grdT((N_NODES + TILE - 1) / TILE);               // 1563 blocks

    // ---- CSR build (by dst)
    zero_kernel<<<dim3((N_NODES / 4 + 255) / 256), blk256, 0, stream>>>((float*)deg, N_NODES / 4);
    hist_kernel<<<grdE, blk256, 0, stream>>>(dst, deg);
    scan_kernel<<<dim3(1), dim3(1024), 0, stream>>>(deg, row_ptr, cursor);
    fill_kernel<<<grdE, blk256, 0, stream>>>(src, dst, cursor, csr);

    // ---- 3 fused GraphConv layers
    fused_layer_kernel<<<grdT, blk256, 0, stream>>>(x, row_ptr, csr, Wr1, br1, Ws1, A);
    fused_layer_kernel<<<grdT, blk256, 0, stream>>>(A, row_ptr, csr, Wr2, br2, Ws2, B);
    fused_layer_kernel<<<grdT, blk256, 0, stream>>>(B, row_ptr, csr, Wr3, br3, Ws3, A);

    // ---- pool + head
    zero_kernel<<<dim3((N_GRAPHS * D / 4 + 255) / 256), blk256, 0, stream>>>(g, N_GRAPHS * D / 4);
    pool_kernel<<<dim3((N_NODES + 63) / 64), dim3(64), 0, stream>>>(A, batch, g);
    head_kernel<<<dim3(N_GRAPHS), dim3(64), 0, stream>>>(g, Wfc1, bfc1, Wfc2, bfc2, (float*)d_out);
}

// Round 3
// 560.898 us; speedup vs baseline: 6.2189x; 1.3877x over previous
//
#include <hip/hip_runtime.h>

#define N_NODES   100000
#define N_EDGES   1200000
#define D         64
#define N_GRAPHS  128
#define N_CLASSES 3

#define TILE      64          // nodes per block in fused layer
#define LSTRIDE   68          // 64 + 4 pad

#define SCAN_CHUNK 512
#define SCAN_NB    ((N_NODES + SCAN_CHUNK - 1) / SCAN_CHUNK)   // 196 (<=256)

// ---------------------------------------------------------------- zero buffer
__global__ void zero_kernel(float* __restrict__ p, int n4) {
    int i = blockIdx.x * blockDim.x + threadIdx.x;
    if (i < n4) ((float4*)p)[i] = make_float4(0.f, 0.f, 0.f, 0.f);
}

// -------------------------------------------------------------- CSR build: deg
__global__ __launch_bounds__(256) void hist_kernel(
        const int* __restrict__ dst, int* __restrict__ deg) {
    int e = blockIdx.x * blockDim.x + threadIdx.x;
    if (e < N_EDGES) atomicAdd(&deg[dst[e]], 1);
}

// ----------------------------------------------- scan phase 1: chunk partials
__global__ __launch_bounds__(256) void scan_partials_kernel(
        const int* __restrict__ deg, int* __restrict__ partial) {
    __shared__ int s[256];
    int b = blockIdx.x, t = threadIdx.x;
    int base = b * SCAN_CHUNK + t * 2;
    int v = 0;
    if (base     < N_NODES) v += deg[base];
    if (base + 1 < N_NODES) v += deg[base + 1];
    s[t] = v;
    __syncthreads();
    for (int d = 128; d > 0; d >>= 1) {
        if (t < d) s[t] += s[t + d];
        __syncthreads();
    }
    if (t == 0) partial[b] = s[0];
}

// ------------------------------------- scan phase 2: exclusive scan, 1 block
__global__ __launch_bounds__(256) void scan_mid_kernel(int* __restrict__ partial) {
    __shared__ int s[256];
    int t = threadIdx.x;
    int v = (t < SCAN_NB) ? partial[t] : 0;
    s[t] = v;
    __syncthreads();
    for (int d = 1; d < 256; d <<= 1) {
        int u = (t >= d) ? s[t - d] : 0;
        __syncthreads();
        s[t] += u;
        __syncthreads();
    }
    if (t < SCAN_NB) partial[t] = s[t] - v;   // exclusive
}

// ----------------------------------- scan phase 3: emit row_ptr/cursor
__global__ __launch_bounds__(256) void scan_emit_kernel(
        const int* __restrict__ deg, const int* __restrict__ partial,
        int* __restrict__ row_ptr, int* __restrict__ cursor) {
    __shared__ int s[256];
    int b = blockIdx.x, t = threadIdx.x;
    int base = b * SCAN_CHUNK + t * 2;
    int d0 = (base     < N_NODES) ? deg[base]     : 0;
    int d1 = (base + 1 < N_NODES) ? deg[base + 1] : 0;
    int local = d0 + d1;
    s[t] = local;
    __syncthreads();
    for (int d = 1; d < 256; d <<= 1) {
        int u = (t >= d) ? s[t - d] : 0;
        __syncthreads();
        s[t] += u;
        __syncthreads();
    }
    int off = partial[b] + s[t] - local;      // exclusive prefix for this pair
    if (base < N_NODES)     { row_ptr[base]     = off;      cursor[base]     = off; }
    if (base + 1 < N_NODES) { row_ptr[base + 1] = off + d0; cursor[base + 1] = off + d0; }
    if (b == 0 && t == 0) row_ptr[N_NODES] = N_EDGES;
}

// -------------------------------------------------------------- CSR build: fill
__global__ __launch_bounds__(256) void fill_kernel(
        const int* __restrict__ src, const int* __restrict__ dst,
        int* __restrict__ cursor, int* __restrict__ csr) {
    int e = blockIdx.x * blockDim.x + threadIdx.x;
    if (e < N_EDGES) {
        int p = atomicAdd(&cursor[dst[e]], 1);
        csr[p] = src[e];
    }
}

// --------------------------- fused layer: gather + agg@Wr + h@Ws + br, relu
__global__ __launch_bounds__(256) void fused_layer_kernel(
        const float* __restrict__ hin,
        const int* __restrict__ row_ptr,
        const int* __restrict__ csr,
        const float* __restrict__ Wr,
        const float* __restrict__ br,
        const float* __restrict__ Ws,
        float* __restrict__ hout) {
    __shared__ float WrS[D * D];
    __shared__ float WsS[D * D];
    __shared__ float aggS[TILE * LSTRIDE];
    __shared__ float xS[TILE * LSTRIDE];

    int tid = threadIdx.x;
    for (int i = tid; i < D * D; i += 256) {
        WrS[i] = Wr[i];
        WsS[i] = Ws[i];
    }

    const int f4    = (tid & 15) * 4;
    const int node0 = blockIdx.x * TILE;

    for (int r = 0; r < 4; ++r) {
        int ln = r * 16 + (tid >> 4);
        int n  = node0 + ln;
        float ax = 0.f, ay = 0.f, az = 0.f, aw = 0.f;
        float bx = 0.f, by = 0.f, bz = 0.f, bw = 0.f;
        float cx = 0.f, cy = 0.f, cz = 0.f, cw = 0.f;
        float dx = 0.f, dy = 0.f, dz = 0.f, dw = 0.f;
        if (n < N_NODES) {
            float4 xv = *(const float4*)(hin + (size_t)n * D + f4);
            *(float4*)&xS[ln * LSTRIDE + f4] = xv;
            int beg = row_ptr[n];
            int end = row_ptr[n + 1];
            int j = beg;
            for (; j + 4 <= end; j += 4) {
                int s0 = csr[j + 0], s1 = csr[j + 1];
                int s2 = csr[j + 2], s3 = csr[j + 3];
                float4 v0 = *(const float4*)(hin + (size_t)s0 * D + f4);
                float4 v1 = *(const float4*)(hin + (size_t)s1 * D + f4);
                float4 v2 = *(const float4*)(hin + (size_t)s2 * D + f4);
                float4 v3 = *(const float4*)(hin + (size_t)s3 * D + f4);
                ax += v0.x; ay += v0.y; az += v0.z; aw += v0.w;
                bx += v1.x; by += v1.y; bz += v1.z; bw += v1.w;
                cx += v2.x; cy += v2.y; cz += v2.z; cw += v2.w;
                dx += v3.x; dy += v3.y; dz += v3.z; dw += v3.w;
            }
            for (; j < end; ++j) {
                float4 v = *(const float4*)(hin + (size_t)csr[j] * D + f4);
                ax += v.x; ay += v.y; az += v.z; aw += v.w;
            }
        } else {
            *(float4*)&xS[ln * LSTRIDE + f4] = make_float4(0.f, 0.f, 0.f, 0.f);
        }
        float4 acc = make_float4(ax + bx + cx + dx, ay + by + cy + dy,
                                 az + bz + cz + dz, aw + bw + cw + dw);
        *(float4*)&aggS[ln * LSTRIDE + f4] = acc;
    }
    __syncthreads();

    const int q = tid >> 4;
    float4 bias = *(const float4*)(br + f4);
    float4 c0 = bias, c1 = bias, c2 = bias, c3 = bias;

#pragma unroll 4
    for (int k = 0; k < D; ++k) {
        float4 wr = *(const float4*)&WrS[k * D + f4];
        float4 ws = *(const float4*)&WsS[k * D + f4];
        float a0 = aggS[(4 * q + 0) * LSTRIDE + k];
        float a1 = aggS[(4 * q + 1) * LSTRIDE + k];
        float a2 = aggS[(4 * q + 2) * LSTRIDE + k];
        float a3 = aggS[(4 * q + 3) * LSTRIDE + k];
        float x0 = xS[(4 * q + 0) * LSTRIDE + k];
        float x1 = xS[(4 * q + 1) * LSTRIDE + k];
        float x2 = xS[(4 * q + 2) * LSTRIDE + k];
        float x3 = xS[(4 * q + 3) * LSTRIDE + k];
        c0.x += a0 * wr.x + x0 * ws.x;  c0.y += a0 * wr.y + x0 * ws.y;
        c0.z += a0 * wr.z + x0 * ws.z;  c0.w += a0 * wr.w + x0 * ws.w;
        c1.x += a1 * wr.x + x1 * ws.x;  c1.y += a1 * wr.y + x1 * ws.y;
        c1.z += a1 * wr.z + x1 * ws.z;  c1.w += a1 * wr.w + x1 * ws.w;
        c2.x += a2 * wr.x + x2 * ws.x;  c2.y += a2 * wr.y + x2 * ws.y;
        c2.z += a2 * wr.z + x2 * ws.z;  c2.w += a2 * wr.w + x2 * ws.w;
        c3.x += a3 * wr.x + x3 * ws.x;  c3.y += a3 * wr.y + x3 * ws.y;
        c3.z += a3 * wr.z + x3 * ws.z;  c3.w += a3 * wr.w + x3 * ws.w;
    }

    float4 cc[4] = {c0, c1, c2, c3};
#pragma unroll
    for (int i = 0; i < 4; ++i) {
        int n = node0 + 4 * q + i;
        if (n < N_NODES) {
            float4 o;
            o.x = fmaxf(cc[i].x, 0.f); o.y = fmaxf(cc[i].y, 0.f);
            o.z = fmaxf(cc[i].z, 0.f); o.w = fmaxf(cc[i].w, 0.f);
            *(float4*)(hout + (size_t)n * D + f4) = o;
        }
    }
}

// ------------------------------------------------- pool: segment_sum by batch
__global__ __launch_bounds__(64) void pool_kernel(
        const float* __restrict__ h,
        const int* __restrict__ batch,
        float* __restrict__ g) {
    int n0 = blockIdx.x * 64;
    int f  = threadIdx.x;
    if (n0 >= N_NODES) return;
    float acc = 0.f;
    int cur = batch[n0];
    int nend = n0 + 64;
    if (nend > N_NODES) nend = N_NODES;
    for (int n = n0; n < nend; ++n) {
        int b = batch[n];
        if (b != cur) {
            atomicAdd(&g[cur * D + f], acc);
            acc = 0.f;
            cur = b;
        }
        acc += h[(size_t)n * D + f];
    }
    atomicAdd(&g[cur * D + f], acc);
}

// ------------------------------------------------------------------- MLP head
__global__ __launch_bounds__(64) void head_kernel(
        const float* __restrict__ g,
        const float* __restrict__ Wfc1, const float* __restrict__ bfc1,
        const float* __restrict__ Wfc2, const float* __restrict__ bfc2,
        float* __restrict__ out) {
    __shared__ float hS[D];
    __shared__ float lS[N_CLASSES];
    int gr = blockIdx.x;
    int f  = threadIdx.x;

    float acc = bfc1[f];
#pragma unroll
    for (int k = 0; k < D; ++k) acc += g[gr * D + k] * Wfc1[k * D + f];
    hS[f] = fmaxf(acc, 0.f);
    __syncthreads();

    if (f < N_CLASSES) {
        float a = bfc2[f];
#pragma unroll
        for (int k = 0; k < D; ++k) a += hS[k] * Wfc2[k * N_CLASSES + f];
        lS[f] = a;
    }
    __syncthreads();

    if (f == 0) {
        float m = fmaxf(lS[0], fmaxf(lS[1], lS[2]));
        float s = expf(lS[0] - m) + expf(lS[1] - m) + expf(lS[2] - m);
        float lse = m + logf(s);
        out[gr * 3 + 0] = lS[0] - lse;
        out[gr * 3 + 1] = lS[1] - lse;
        out[gr * 3 + 2] = lS[2] - lse;
    }
}

// ---------------------------------------------------------------------- launch
extern "C" void kernel_launch(void* const* d_in, const int* in_sizes, int n_in,
                              void* d_out, int out_size, void* d_ws, size_t ws_size,
                              hipStream_t stream) {
    const float* x     = (const float*)d_in[0];
    const int*   edge  = (const int*)d_in[1];
    const int*   batch = (const int*)d_in[2];
    const float* Wr1 = (const float*)d_in[3];
    const float* br1 = (const float*)d_in[4];
    const float* Ws1 = (const float*)d_in[5];
    const float* Wr2 = (const float*)d_in[6];
    const float* br2 = (const float*)d_in[7];
    const float* Ws2 = (const float*)d_in[8];
    const float* Wr3 = (const float*)d_in[9];
    const float* br3 = (const float*)d_in[10];
    const float* Ws3 = (const float*)d_in[11];
    const float* Wfc1 = (const float*)d_in[12];
    const float* bfc1 = (const float*)d_in[13];
    const float* Wfc2 = (const float*)d_in[14];
    const float* bfc2 = (const float*)d_in[15];

    const int* src = edge;
    const int* dst = edge + N_EDGES;

    // workspace layout
    float* A       = (float*)d_ws;                        // 6,400,000 f
    float* B       = A + (size_t)N_NODES * D;             // 6,400,000 f
    float* g       = B + (size_t)N_NODES * D;             //     8,192 f
    int*   deg     = (int*)(g + (size_t)N_GRAPHS * D);    //   100,000 i
    int*   row_ptr = deg + N_NODES;                       //   100,001 i
    int*   cursor  = row_ptr + (N_NODES + 1);             //   100,000 i
    int*   csr     = cursor + N_NODES;                    // 1,200,000 i
    int*   partial = csr + N_EDGES;                       //       256 i

    dim3 blk256(256);
    dim3 grdE((N_EDGES + 255) / 256);
    dim3 grdT((N_NODES + TILE - 1) / TILE);

    // ---- CSR build (by dst)
    zero_kernel<<<dim3((N_NODES / 4 + 255) / 256), blk256, 0, stream>>>((float*)deg, N_NODES / 4);
    hist_kernel<<<grdE, blk256, 0, stream>>>(dst, deg);
    scan_partials_kernel<<<dim3(SCAN_NB), blk256, 0, stream>>>(deg, partial);
    scan_mid_kernel<<<dim3(1), blk256, 0, stream>>>(partial);
    scan_emit_kernel<<<dim3(SCAN_NB), blk256, 0, stream>>>(deg, partial, row_ptr, cursor);
    fill_kernel<<<grdE, blk256, 0, stream>>>(src, dst, cursor, csr);

    // ---- 3 fused GraphConv layers
    fused_layer_kernel<<<grdT, blk256, 0, stream>>>(x, row_ptr, csr, Wr1, br1, Ws1, A);
    fused_layer_kernel<<<grdT, blk256, 0, stream>>>(A, row_ptr, csr, Wr2, br2, Ws2, B);
    fused_layer_kernel<<<grdT, blk256, 0, stream>>>(B, row_ptr, csr, Wr3, br3, Ws3, A);

    // ---- pool + head
    zero_kernel<<<dim3((N_GRAPHS * D / 4 + 255) / 256), blk256, 0, stream>>>(g, N_GRAPHS * D / 4);
    pool_kernel<<<dim3((N_NODES + 63) / 64), dim3(64), 0, stream>>>(A, batch, g);
    head_kernel<<<dim3(N_GRAPHS), dim3(64), 0, stream>>>(g, Wfc1, bfc1, Wfc2, bfc2, (float*)d_out);
}

// Round 4
// 521.192 us; speedup vs baseline: 6.6927x; 1.0762x over previous
//
#include <hip/hip_runtime.h>

#define N_NODES   100000
#define N_EDGES   1200000
#define D         64
#define N_GRAPHS  128
#define N_CLASSES 3

#define TILE      64          // nodes per block in fused layer
#define LSTRIDE   68          // 64 + 4 pad

#define SCAN_CHUNK 512
#define SCAN_NB    ((N_NODES + SCAN_CHUNK - 1) / SCAN_CHUNK)   // 196 (<=256)

// ---------------------------------------------------------------- zero buffer
__global__ void zero_kernel(float* __restrict__ p, int n4) {
    int i = blockIdx.x * blockDim.x + threadIdx.x;
    if (i < n4) ((float4*)p)[i] = make_float4(0.f, 0.f, 0.f, 0.f);
}

// -------------------------------------------------------------- CSR build: deg
__global__ __launch_bounds__(256) void hist_kernel(
        const int* __restrict__ dst, int* __restrict__ deg) {
    int i = blockIdx.x * blockDim.x + threadIdx.x;     // i indexes edge quads
    int e = i * 4;
    if (e + 3 < N_EDGES) {
        int4 d = *(const int4*)(dst + e);
        atomicAdd(&deg[d.x], 1);
        atomicAdd(&deg[d.y], 1);
        atomicAdd(&deg[d.z], 1);
        atomicAdd(&deg[d.w], 1);
    } else {
        for (; e < N_EDGES; ++e) atomicAdd(&deg[dst[e]], 1);
    }
}

// ----------------------------------------------- scan phase 1: chunk partials
__global__ __launch_bounds__(256) void scan_partials_kernel(
        const int* __restrict__ deg, int* __restrict__ partial) {
    __shared__ int s[256];
    int b = blockIdx.x, t = threadIdx.x;
    int base = b * SCAN_CHUNK + t * 2;
    int v = 0;
    if (base     < N_NODES) v += deg[base];
    if (base + 1 < N_NODES) v += deg[base + 1];
    s[t] = v;
    __syncthreads();
    for (int d = 128; d > 0; d >>= 1) {
        if (t < d) s[t] += s[t + d];
        __syncthreads();
    }
    if (t == 0) partial[b] = s[0];
}

// ------------------------------------- scan phase 2: exclusive scan, 1 block
__global__ __launch_bounds__(256) void scan_mid_kernel(int* __restrict__ partial) {
    __shared__ int s[256];
    int t = threadIdx.x;
    int v = (t < SCAN_NB) ? partial[t] : 0;
    s[t] = v;
    __syncthreads();
    for (int d = 1; d < 256; d <<= 1) {
        int u = (t >= d) ? s[t - d] : 0;
        __syncthreads();
        s[t] += u;
        __syncthreads();
    }
    if (t < SCAN_NB) partial[t] = s[t] - v;   // exclusive
}

// ----------------------------------- scan phase 3: emit row_ptr/cursor
__global__ __launch_bounds__(256) void scan_emit_kernel(
        const int* __restrict__ deg, const int* __restrict__ partial,
        int* __restrict__ row_ptr, int* __restrict__ cursor) {
    __shared__ int s[256];
    int b = blockIdx.x, t = threadIdx.x;
    int base = b * SCAN_CHUNK + t * 2;
    int d0 = (base     < N_NODES) ? deg[base]     : 0;
    int d1 = (base + 1 < N_NODES) ? deg[base + 1] : 0;
    int local = d0 + d1;
    s[t] = local;
    __syncthreads();
    for (int d = 1; d < 256; d <<= 1) {
        int u = (t >= d) ? s[t - d] : 0;
        __syncthreads();
        s[t] += u;
        __syncthreads();
    }
    int off = partial[b] + s[t] - local;
    if (base < N_NODES)     { row_ptr[base]     = off;      cursor[base]     = off; }
    if (base + 1 < N_NODES) { row_ptr[base + 1] = off + d0; cursor[base + 1] = off + d0; }
    if (b == 0 && t == 0) row_ptr[N_NODES] = N_EDGES;
}

// -------------------------------------------------------------- CSR build: fill
__global__ __launch_bounds__(256) void fill_kernel(
        const int* __restrict__ src, const int* __restrict__ dst,
        int* __restrict__ cursor, int* __restrict__ csr) {
    int i = blockIdx.x * blockDim.x + threadIdx.x;
    int e = i * 4;
    if (e + 3 < N_EDGES) {
        int4 d = *(const int4*)(dst + e);
        int4 s = *(const int4*)(src + e);
        int p0 = atomicAdd(&cursor[d.x], 1); csr[p0] = s.x;
        int p1 = atomicAdd(&cursor[d.y], 1); csr[p1] = s.y;
        int p2 = atomicAdd(&cursor[d.z], 1); csr[p2] = s.z;
        int p3 = atomicAdd(&cursor[d.w], 1); csr[p3] = s.w;
    } else {
        for (; e < N_EDGES; ++e) {
            int p = atomicAdd(&cursor[dst[e]], 1);
            csr[p] = src[e];
        }
    }
}

// --------------------------- fused layer: gather + agg@Wr + h@Ws + br, relu
// Weights read from global (L1-resident) -> LDS only 2 tiles = 35 KB -> 4 blk/CU.
// DO_POOL: layer-3 variant that pools its relu output into g instead of
// writing hout (batch is sorted; block-local segmented reduce + few atomics).
template<int DO_POOL>
__global__ __launch_bounds__(256, 4) void fused_layer_kernel(
        const float* __restrict__ hin,
        const int* __restrict__ row_ptr,
        const int* __restrict__ csr,
        const float* __restrict__ Wr,
        const float* __restrict__ br,
        const float* __restrict__ Ws,
        float* __restrict__ hout,
        const int* __restrict__ batch,
        float* __restrict__ g) {
    __shared__ float aggS[TILE * LSTRIDE];
    __shared__ float xS[TILE * LSTRIDE];
    __shared__ int   bS[TILE];

    const int tid   = threadIdx.x;
    const int f4    = (tid & 15) * 4;
    const int node0 = blockIdx.x * TILE;

    if (DO_POOL && tid < TILE) {
        int n = node0 + tid;
        bS[tid] = (n < N_NODES) ? batch[n] : -1;
    }

    // ---- gather + x staging: 4 rounds x 16 nodes
    for (int r = 0; r < 4; ++r) {
        int ln = r * 16 + (tid >> 4);
        int n  = node0 + ln;
        float ax = 0.f, ay = 0.f, az = 0.f, aw = 0.f;
        float bx = 0.f, by = 0.f, bz = 0.f, bw = 0.f;
        float cx = 0.f, cy = 0.f, cz = 0.f, cw = 0.f;
        float dx = 0.f, dy = 0.f, dz = 0.f, dw = 0.f;
        if (n < N_NODES) {
            float4 xv = *(const float4*)(hin + (size_t)n * D + f4);
            *(float4*)&xS[ln * LSTRIDE + f4] = xv;
            int beg = row_ptr[n];
            int end = row_ptr[n + 1];
            int j = beg;
            for (; j + 4 <= end; j += 4) {
                int s0 = csr[j + 0], s1 = csr[j + 1];
                int s2 = csr[j + 2], s3 = csr[j + 3];
                float4 v0 = *(const float4*)(hin + (size_t)s0 * D + f4);
                float4 v1 = *(const float4*)(hin + (size_t)s1 * D + f4);
                float4 v2 = *(const float4*)(hin + (size_t)s2 * D + f4);
                float4 v3 = *(const float4*)(hin + (size_t)s3 * D + f4);
                ax += v0.x; ay += v0.y; az += v0.z; aw += v0.w;
                bx += v1.x; by += v1.y; bz += v1.z; bw += v1.w;
                cx += v2.x; cy += v2.y; cz += v2.z; cw += v2.w;
                dx += v3.x; dy += v3.y; dz += v3.z; dw += v3.w;
            }
            for (; j < end; ++j) {
                float4 v = *(const float4*)(hin + (size_t)csr[j] * D + f4);
                ax += v.x; ay += v.y; az += v.z; aw += v.w;
            }
        } else {
            *(float4*)&xS[ln * LSTRIDE + f4] = make_float4(0.f, 0.f, 0.f, 0.f);
        }
        float4 acc = make_float4(ax + bx + cx + dx, ay + by + cy + dy,
                                 az + bz + cz + dz, aw + bw + cw + dw);
        *(float4*)&aggS[ln * LSTRIDE + f4] = acc;
    }
    __syncthreads();

    // ---- GEMM: thread = (node-quad q, feature-quad f4); weights from global
    const int q  = tid >> 4;
    const int fq = tid & 15;
    const float4* Wr4 = (const float4*)Wr;   // [k][fq] -> Wr4[k*16+fq]
    const float4* Ws4 = (const float4*)Ws;
    float4 bias = *(const float4*)(br + f4);
    float4 c0 = bias, c1 = bias, c2 = bias, c3 = bias;

#pragma unroll 8
    for (int k = 0; k < D; ++k) {
        float4 wr = Wr4[k * 16 + fq];
        float4 ws = Ws4[k * 16 + fq];
        float a0 = aggS[(4 * q + 0) * LSTRIDE + k];
        float a1 = aggS[(4 * q + 1) * LSTRIDE + k];
        float a2 = aggS[(4 * q + 2) * LSTRIDE + k];
        float a3 = aggS[(4 * q + 3) * LSTRIDE + k];
        float x0 = xS[(4 * q + 0) * LSTRIDE + k];
        float x1 = xS[(4 * q + 1) * LSTRIDE + k];
        float x2 = xS[(4 * q + 2) * LSTRIDE + k];
        float x3 = xS[(4 * q + 3) * LSTRIDE + k];
        c0.x += a0 * wr.x + x0 * ws.x;  c0.y += a0 * wr.y + x0 * ws.y;
        c0.z += a0 * wr.z + x0 * ws.z;  c0.w += a0 * wr.w + x0 * ws.w;
        c1.x += a1 * wr.x + x1 * ws.x;  c1.y += a1 * wr.y + x1 * ws.y;
        c1.z += a1 * wr.z + x1 * ws.z;  c1.w += a1 * wr.w + x1 * ws.w;
        c2.x += a2 * wr.x + x2 * ws.x;  c2.y += a2 * wr.y + x2 * ws.y;
        c2.z += a2 * wr.z + x2 * ws.z;  c2.w += a2 * wr.w + x2 * ws.w;
        c3.x += a3 * wr.x + x3 * ws.x;  c3.y += a3 * wr.y + x3 * ws.y;
        c3.z += a3 * wr.z + x3 * ws.z;  c3.w += a3 * wr.w + x3 * ws.w;
    }

    float4 cc[4] = {c0, c1, c2, c3};

    if (!DO_POOL) {
#pragma unroll
        for (int i = 0; i < 4; ++i) {
            int n = node0 + 4 * q + i;
            if (n < N_NODES) {
                float4 o;
                o.x = fmaxf(cc[i].x, 0.f); o.y = fmaxf(cc[i].y, 0.f);
                o.z = fmaxf(cc[i].z, 0.f); o.w = fmaxf(cc[i].w, 0.f);
                *(float4*)(hout + (size_t)n * D + f4) = o;
            }
        }
    } else {
        // park relu output back in aggS, then segmented column-reduce
        __syncthreads();   // everyone done reading aggS/xS
#pragma unroll
        for (int i = 0; i < 4; ++i) {
            float4 o;
            o.x = fmaxf(cc[i].x, 0.f); o.y = fmaxf(cc[i].y, 0.f);
            o.z = fmaxf(cc[i].z, 0.f); o.w = fmaxf(cc[i].w, 0.f);
            *(float4*)&aggS[(4 * q + i) * LSTRIDE + f4] = o;
        }
        __syncthreads();
        // thread t: feature f = t&63, node segment part = t>>6 (16 nodes)
        int f    = tid & 63;
        int part = tid >> 6;
        int ln0  = part * 16;
        int cur  = bS[ln0];
        float acc = 0.f;
        for (int ln = ln0; ln < ln0 + 16; ++ln) {
            int b = bS[ln];
            if (b < 0) break;                       // sorted: invalid tail only
            if (b != cur) {
                atomicAdd(&g[cur * D + f], acc);
                acc = 0.f;
                cur = b;
            }
            acc += aggS[ln * LSTRIDE + f];
        }
        if (cur >= 0) atomicAdd(&g[cur * D + f], acc);
    }
}

// ------------------------------------------------------------------- MLP head
__global__ __launch_bounds__(64) void head_kernel(
        const float* __restrict__ g,
        const float* __restrict__ Wfc1, const float* __restrict__ bfc1,
        const float* __restrict__ Wfc2, const float* __restrict__ bfc2,
        float* __restrict__ out) {
    __shared__ float hS[D];
    __shared__ float lS[N_CLASSES];
    int gr = blockIdx.x;
    int f  = threadIdx.x;

    float acc = bfc1[f];
#pragma unroll
    for (int k = 0; k < D; ++k) acc += g[gr * D + k] * Wfc1[k * D + f];
    hS[f] = fmaxf(acc, 0.f);
    __syncthreads();

    if (f < N_CLASSES) {
        float a = bfc2[f];
#pragma unroll
        for (int k = 0; k < D; ++k) a += hS[k] * Wfc2[k * N_CLASSES + f];
        lS[f] = a;
    }
    __syncthreads();

    if (f == 0) {
        float m = fmaxf(lS[0], fmaxf(lS[1], lS[2]));
        float s = expf(lS[0] - m) + expf(lS[1] - m) + expf(lS[2] - m);
        float lse = m + logf(s);
        out[gr * 3 + 0] = lS[0] - lse;
        out[gr * 3 + 1] = lS[1] - lse;
        out[gr * 3 + 2] = lS[2] - lse;
    }
}

// ---------------------------------------------------------------------- launch
extern "C" void kernel_launch(void* const* d_in, const int* in_sizes, int n_in,
                              void* d_out, int out_size, void* d_ws, size_t ws_size,
                              hipStream_t stream) {
    const float* x     = (const float*)d_in[0];
    const int*   edge  = (const int*)d_in[1];
    const int*   batch = (const int*)d_in[2];
    const float* Wr1 = (const float*)d_in[3];
    const float* br1 = (const float*)d_in[4];
    const float* Ws1 = (const float*)d_in[5];
    const float* Wr2 = (const float*)d_in[6];
    const float* br2 = (const float*)d_in[7];
    const float* Ws2 = (const float*)d_in[8];
    const float* Wr3 = (const float*)d_in[9];
    const float* br3 = (const float*)d_in[10];
    const float* Ws3 = (const float*)d_in[11];
    const float* Wfc1 = (const float*)d_in[12];
    const float* bfc1 = (const float*)d_in[13];
    const float* Wfc2 = (const float*)d_in[14];
    const float* bfc2 = (const float*)d_in[15];

    const int* src = edge;
    const int* dst = edge + N_EDGES;

    // workspace layout
    float* A       = (float*)d_ws;                        // 6,400,000 f
    float* B       = A + (size_t)N_NODES * D;             // 6,400,000 f
    float* g       = B + (size_t)N_NODES * D;             //     8,192 f
    int*   deg     = (int*)(g + (size_t)N_GRAPHS * D);    //   100,000 i
    int*   row_ptr = deg + N_NODES;                       //   100,001 i
    int*   cursor  = row_ptr + (N_NODES + 1);             //   100,000 i
    int*   csr     = cursor + N_NODES;                    // 1,200,000 i
    int*   partial = csr + N_EDGES;                       //       256 i

    dim3 blk256(256);
    dim3 grdE4((N_EDGES / 4 + 255) / 256);
    dim3 grdT((N_NODES + TILE - 1) / TILE);

    // ---- CSR build (by dst)
    zero_kernel<<<dim3((N_NODES / 4 + 255) / 256), blk256, 0, stream>>>((float*)deg, N_NODES / 4);
    hist_kernel<<<grdE4, blk256, 0, stream>>>(dst, deg);
    scan_partials_kernel<<<dim3(SCAN_NB), blk256, 0, stream>>>(deg, partial);
    scan_mid_kernel<<<dim3(1), blk256, 0, stream>>>(partial);
    scan_emit_kernel<<<dim3(SCAN_NB), blk256, 0, stream>>>(deg, partial, row_ptr, cursor);
    fill_kernel<<<grdE4, blk256, 0, stream>>>(src, dst, cursor, csr);

    // zero pooled buffer early (needed by layer-3 fused pool)
    zero_kernel<<<dim3((N_GRAPHS * D / 4 + 255) / 256), blk256, 0, stream>>>(g, N_GRAPHS * D / 4);

    // ---- 3 fused GraphConv layers (layer 3 pools directly into g)
    fused_layer_kernel<0><<<grdT, blk256, 0, stream>>>(x, row_ptr, csr, Wr1, br1, Ws1, A, batch, g);
    fused_layer_kernel<0><<<grdT, blk256, 0, stream>>>(A, row_ptr, csr, Wr2, br2, Ws2, B, batch, g);
    fused_layer_kernel<1><<<grdT, blk256, 0, stream>>>(B, row_ptr, csr, Wr3, br3, Ws3, A, batch, g);

    // ---- head
    head_kernel<<<dim3(N_GRAPHS), dim3(64), 0, stream>>>(g, Wfc1, bfc1, Wfc2, bfc2, (float*)d_out);
}

// Round 5
// 470.324 us; speedup vs baseline: 7.4165x; 1.1082x over previous
//
#include <hip/hip_runtime.h>

#define N_NODES   100000
#define N_EDGES   1200000
#define D         64
#define N_GRAPHS  128
#define N_CLASSES 3

#define TILE      64          // nodes per block in fused layer
#define LSTRIDE   68          // 64 + 4 pad (floats)

#define SCAN_CHUNK 512
#define SCAN_NB    ((N_NODES + SCAN_CHUNK - 1) / SCAN_CHUNK)   // 196 (<=256)

typedef unsigned int  uint;
typedef unsigned short ushort;

// ------------------------------------------------------------- bf16 helpers
__device__ __forceinline__ ushort bf16_rne(float f) {
    uint u = __float_as_uint(f);
    u += 0x7FFFu + ((u >> 16) & 1u);      // round to nearest even
    return (ushort)(u >> 16);
}
__device__ __forceinline__ void unpack8(float* o, uint4 v) {
    o[0] = __uint_as_float(v.x << 16);
    o[1] = __uint_as_float(v.x & 0xFFFF0000u);
    o[2] = __uint_as_float(v.y << 16);
    o[3] = __uint_as_float(v.y & 0xFFFF0000u);
    o[4] = __uint_as_float(v.z << 16);
    o[5] = __uint_as_float(v.z & 0xFFFF0000u);
    o[6] = __uint_as_float(v.w << 16);
    o[7] = __uint_as_float(v.w & 0xFFFF0000u);
}
__device__ __forceinline__ void acc8(float* a, uint4 v) {
    a[0] += __uint_as_float(v.x << 16);
    a[1] += __uint_as_float(v.x & 0xFFFF0000u);
    a[2] += __uint_as_float(v.y << 16);
    a[3] += __uint_as_float(v.y & 0xFFFF0000u);
    a[4] += __uint_as_float(v.z << 16);
    a[5] += __uint_as_float(v.z & 0xFFFF0000u);
    a[6] += __uint_as_float(v.w << 16);
    a[7] += __uint_as_float(v.w & 0xFFFF0000u);
}

// ---------------------------------------------------------------- zero buffer
__global__ void zero_kernel(float* __restrict__ p, int n4) {
    int i = blockIdx.x * blockDim.x + threadIdx.x;
    if (i < n4) ((float4*)p)[i] = make_float4(0.f, 0.f, 0.f, 0.f);
}

// ------------------------------------------------------------ f32 -> bf16
__global__ __launch_bounds__(256) void cvt_bf16_kernel(
        const float* __restrict__ in, ushort* __restrict__ out, int n4) {
    int i = blockIdx.x * blockDim.x + threadIdx.x;
    if (i < n4) {
        float4 v = ((const float4*)in)[i];
        ushort4 o;
        o.x = bf16_rne(v.x); o.y = bf16_rne(v.y);
        o.z = bf16_rne(v.z); o.w = bf16_rne(v.w);
        ((ushort4*)out)[i] = o;
    }
}

// -------------------------------------------------------------- CSR build: deg
__global__ __launch_bounds__(256) void hist_kernel(
        const int* __restrict__ dst, int* __restrict__ deg) {
    int i = blockIdx.x * blockDim.x + threadIdx.x;
    int e = i * 4;
    if (e + 3 < N_EDGES) {
        int4 d = *(const int4*)(dst + e);
        atomicAdd(&deg[d.x], 1);
        atomicAdd(&deg[d.y], 1);
        atomicAdd(&deg[d.z], 1);
        atomicAdd(&deg[d.w], 1);
    } else {
        for (; e < N_EDGES; ++e) atomicAdd(&deg[dst[e]], 1);
    }
}

// ----------------------------------------------- scan phase 1: chunk partials
__global__ __launch_bounds__(256) void scan_partials_kernel(
        const int* __restrict__ deg, int* __restrict__ partial) {
    __shared__ int s[256];
    int b = blockIdx.x, t = threadIdx.x;
    int base = b * SCAN_CHUNK + t * 2;
    int v = 0;
    if (base     < N_NODES) v += deg[base];
    if (base + 1 < N_NODES) v += deg[base + 1];
    s[t] = v;
    __syncthreads();
    for (int d = 128; d > 0; d >>= 1) {
        if (t < d) s[t] += s[t + d];
        __syncthreads();
    }
    if (t == 0) partial[b] = s[0];
}

// ------------------------------------- scan phase 2: exclusive scan, 1 block
__global__ __launch_bounds__(256) void scan_mid_kernel(int* __restrict__ partial) {
    __shared__ int s[256];
    int t = threadIdx.x;
    int v = (t < SCAN_NB) ? partial[t] : 0;
    s[t] = v;
    __syncthreads();
    for (int d = 1; d < 256; d <<= 1) {
        int u = (t >= d) ? s[t - d] : 0;
        __syncthreads();
        s[t] += u;
        __syncthreads();
    }
    if (t < SCAN_NB) partial[t] = s[t] - v;   // exclusive
}

// ----------------------------------- scan phase 3: emit row_ptr/cursor
__global__ __launch_bounds__(256) void scan_emit_kernel(
        const int* __restrict__ deg, const int* __restrict__ partial,
        int* __restrict__ row_ptr, int* __restrict__ cursor) {
    __shared__ int s[256];
    int b = blockIdx.x, t = threadIdx.x;
    int base = b * SCAN_CHUNK + t * 2;
    int d0 = (base     < N_NODES) ? deg[base]     : 0;
    int d1 = (base + 1 < N_NODES) ? deg[base + 1] : 0;
    int local = d0 + d1;
    s[t] = local;
    __syncthreads();
    for (int d = 1; d < 256; d <<= 1) {
        int u = (t >= d) ? s[t - d] : 0;
        __syncthreads();
        s[t] += u;
        __syncthreads();
    }
    int off = partial[b] + s[t] - local;
    if (base < N_NODES)     { row_ptr[base]     = off;      cursor[base]     = off; }
    if (base + 1 < N_NODES) { row_ptr[base + 1] = off + d0; cursor[base + 1] = off + d0; }
    if (b == 0 && t == 0) row_ptr[N_NODES] = N_EDGES;
}

// -------------------------------------------------------------- CSR build: fill
__global__ __launch_bounds__(256) void fill_kernel(
        const int* __restrict__ src, const int* __restrict__ dst,
        int* __restrict__ cursor, int* __restrict__ csr) {
    int i = blockIdx.x * blockDim.x + threadIdx.x;
    int e = i * 4;
    if (e + 3 < N_EDGES) {
        int4 d = *(const int4*)(dst + e);
        int4 s = *(const int4*)(src + e);
        int p0 = atomicAdd(&cursor[d.x], 1); csr[p0] = s.x;
        int p1 = atomicAdd(&cursor[d.y], 1); csr[p1] = s.y;
        int p2 = atomicAdd(&cursor[d.z], 1); csr[p2] = s.z;
        int p3 = atomicAdd(&cursor[d.w], 1); csr[p3] = s.w;
    } else {
        for (; e < N_EDGES; ++e) {
            int p = atomicAdd(&cursor[dst[e]], 1);
            csr[p] = src[e];
        }
    }
}

// --------------------------- fused layer: gather + agg@Wr + h@Ws + br, relu
// h stored bf16 (128 B rows -> half the gather traffic); all accumulation f32.
// Weights read from global (L1-resident). DO_POOL: layer-3 pools into g.
template<int DO_POOL>
__global__ __launch_bounds__(256, 4) void fused_layer_kernel(
        const ushort* __restrict__ hin,
        const int* __restrict__ row_ptr,
        const int* __restrict__ csr,
        const float* __restrict__ Wr,
        const float* __restrict__ br,
        const float* __restrict__ Ws,
        ushort* __restrict__ hout,
        const int* __restrict__ batch,
        float* __restrict__ g) {
    __shared__ float aggS[TILE * LSTRIDE];
    __shared__ float xS[TILE * LSTRIDE];
    __shared__ int   bS[TILE];

    const int tid   = threadIdx.x;
    const int node0 = blockIdx.x * TILE;

    if (DO_POOL && tid < TILE) {
        int n = node0 + tid;
        bS[tid] = (n < N_NODES) ? batch[n] : -1;
    }

    // ---- gather: 2 rounds x 32 nodes; thread = (node-slot, 16B-slice of 8 feats)
    const int fq8 = (tid & 7) * 8;
    for (int r = 0; r < 2; ++r) {
        int ln = r * 32 + (tid >> 3);
        int n  = node0 + ln;
        float acc[8] = {0.f, 0.f, 0.f, 0.f, 0.f, 0.f, 0.f, 0.f};
        if (n < N_NODES) {
            uint4 xv = *(const uint4*)(hin + (size_t)n * D + fq8);
            float xr[8];
            unpack8(xr, xv);
            *(float4*)&xS[ln * LSTRIDE + fq8]     = make_float4(xr[0], xr[1], xr[2], xr[3]);
            *(float4*)&xS[ln * LSTRIDE + fq8 + 4] = make_float4(xr[4], xr[5], xr[6], xr[7]);
            int beg = row_ptr[n];
            int end = row_ptr[n + 1];
            int j = beg;
            for (; j + 4 <= end; j += 4) {
                int s0 = csr[j + 0], s1 = csr[j + 1];
                int s2 = csr[j + 2], s3 = csr[j + 3];
                uint4 v0 = *(const uint4*)(hin + (size_t)s0 * D + fq8);
                uint4 v1 = *(const uint4*)(hin + (size_t)s1 * D + fq8);
                uint4 v2 = *(const uint4*)(hin + (size_t)s2 * D + fq8);
                uint4 v3 = *(const uint4*)(hin + (size_t)s3 * D + fq8);
                acc8(acc, v0); acc8(acc, v1); acc8(acc, v2); acc8(acc, v3);
            }
            for (; j < end; ++j) {
                uint4 v = *(const uint4*)(hin + (size_t)csr[j] * D + fq8);
                acc8(acc, v);
            }
        } else {
            *(float4*)&xS[ln * LSTRIDE + fq8]     = make_float4(0.f, 0.f, 0.f, 0.f);
            *(float4*)&xS[ln * LSTRIDE + fq8 + 4] = make_float4(0.f, 0.f, 0.f, 0.f);
        }
        *(float4*)&aggS[ln * LSTRIDE + fq8]     = make_float4(acc[0], acc[1], acc[2], acc[3]);
        *(float4*)&aggS[ln * LSTRIDE + fq8 + 4] = make_float4(acc[4], acc[5], acc[6], acc[7]);
    }
    __syncthreads();

    // ---- GEMM: thread = (node-quad q, feature-quad fq); weights from global
    const int q  = tid >> 4;
    const int fq = tid & 15;
    const int f4 = fq * 4;
    const float4* Wr4 = (const float4*)Wr;   // Wr4[k*16+fq]
    const float4* Ws4 = (const float4*)Ws;
    float4 bias = *(const float4*)(br + f4);
    float4 c0 = bias, c1 = bias, c2 = bias, c3 = bias;

#pragma unroll 8
    for (int k = 0; k < D; ++k) {
        float4 wr = Wr4[k * 16 + fq];
        float4 ws = Ws4[k * 16 + fq];
        float a0 = aggS[(4 * q + 0) * LSTRIDE + k];
        float a1 = aggS[(4 * q + 1) * LSTRIDE + k];
        float a2 = aggS[(4 * q + 2) * LSTRIDE + k];
        float a3 = aggS[(4 * q + 3) * LSTRIDE + k];
        float x0 = xS[(4 * q + 0) * LSTRIDE + k];
        float x1 = xS[(4 * q + 1) * LSTRIDE + k];
        float x2 = xS[(4 * q + 2) * LSTRIDE + k];
        float x3 = xS[(4 * q + 3) * LSTRIDE + k];
        c0.x += a0 * wr.x + x0 * ws.x;  c0.y += a0 * wr.y + x0 * ws.y;
        c0.z += a0 * wr.z + x0 * ws.z;  c0.w += a0 * wr.w + x0 * ws.w;
        c1.x += a1 * wr.x + x1 * ws.x;  c1.y += a1 * wr.y + x1 * ws.y;
        c1.z += a1 * wr.z + x1 * ws.z;  c1.w += a1 * wr.w + x1 * ws.w;
        c2.x += a2 * wr.x + x2 * ws.x;  c2.y += a2 * wr.y + x2 * ws.y;
        c2.z += a2 * wr.z + x2 * ws.z;  c2.w += a2 * wr.w + x2 * ws.w;
        c3.x += a3 * wr.x + x3 * ws.x;  c3.y += a3 * wr.y + x3 * ws.y;
        c3.z += a3 * wr.z + x3 * ws.z;  c3.w += a3 * wr.w + x3 * ws.w;
    }

    float4 cc[4] = {c0, c1, c2, c3};

    if (!DO_POOL) {
#pragma unroll
        for (int i = 0; i < 4; ++i) {
            int n = node0 + 4 * q + i;
            if (n < N_NODES) {
                ushort4 o;
                o.x = bf16_rne(fmaxf(cc[i].x, 0.f));
                o.y = bf16_rne(fmaxf(cc[i].y, 0.f));
                o.z = bf16_rne(fmaxf(cc[i].z, 0.f));
                o.w = bf16_rne(fmaxf(cc[i].w, 0.f));
                *(ushort4*)(hout + (size_t)n * D + f4) = o;
            }
        }
    } else {
        __syncthreads();   // everyone done reading aggS/xS
#pragma unroll
        for (int i = 0; i < 4; ++i) {
            float4 o;
            o.x = fmaxf(cc[i].x, 0.f); o.y = fmaxf(cc[i].y, 0.f);
            o.z = fmaxf(cc[i].z, 0.f); o.w = fmaxf(cc[i].w, 0.f);
            *(float4*)&aggS[(4 * q + i) * LSTRIDE + f4] = o;
        }
        __syncthreads();
        int f    = tid & 63;
        int part = tid >> 6;
        int ln0  = part * 16;
        int cur  = bS[ln0];
        float acc = 0.f;
        for (int ln = ln0; ln < ln0 + 16; ++ln) {
            int b = bS[ln];
            if (b < 0) break;
            if (b != cur) {
                atomicAdd(&g[cur * D + f], acc);
                acc = 0.f;
                cur = b;
            }
            acc += aggS[ln * LSTRIDE + f];
        }
        if (cur >= 0) atomicAdd(&g[cur * D + f], acc);
    }
}

// ------------------------------------------------------------------- MLP head
__global__ __launch_bounds__(64) void head_kernel(
        const float* __restrict__ g,
        const float* __restrict__ Wfc1, const float* __restrict__ bfc1,
        const float* __restrict__ Wfc2, const float* __restrict__ bfc2,
        float* __restrict__ out) {
    __shared__ float hS[D];
    __shared__ float lS[N_CLASSES];
    int gr = blockIdx.x;
    int f  = threadIdx.x;

    float acc = bfc1[f];
#pragma unroll
    for (int k = 0; k < D; ++k) acc += g[gr * D + k] * Wfc1[k * D + f];
    hS[f] = fmaxf(acc, 0.f);
    __syncthreads();

    if (f < N_CLASSES) {
        float a = bfc2[f];
#pragma unroll
        for (int k = 0; k < D; ++k) a += hS[k] * Wfc2[k * N_CLASSES + f];
        lS[f] = a;
    }
    __syncthreads();

    if (f == 0) {
        float m = fmaxf(lS[0], fmaxf(lS[1], lS[2]));
        float s = expf(lS[0] - m) + expf(lS[1] - m) + expf(lS[2] - m);
        float lse = m + logf(s);
        out[gr * 3 + 0] = lS[0] - lse;
        out[gr * 3 + 1] = lS[1] - lse;
        out[gr * 3 + 2] = lS[2] - lse;
    }
}

// ---------------------------------------------------------------------- launch
extern "C" void kernel_launch(void* const* d_in, const int* in_sizes, int n_in,
                              void* d_out, int out_size, void* d_ws, size_t ws_size,
                              hipStream_t stream) {
    const float* x     = (const float*)d_in[0];
    const int*   edge  = (const int*)d_in[1];
    const int*   batch = (const int*)d_in[2];
    const float* Wr1 = (const float*)d_in[3];
    const float* br1 = (const float*)d_in[4];
    const float* Ws1 = (const float*)d_in[5];
    const float* Wr2 = (const float*)d_in[6];
    const float* br2 = (const float*)d_in[7];
    const float* Ws2 = (const float*)d_in[8];
    const float* Wr3 = (const float*)d_in[9];
    const float* br3 = (const float*)d_in[10];
    const float* Ws3 = (const float*)d_in[11];
    const float* Wfc1 = (const float*)d_in[12];
    const float* bfc1 = (const float*)d_in[13];
    const float* Wfc2 = (const float*)d_in[14];
    const float* bfc2 = (const float*)d_in[15];

    const int* src = edge;
    const int* dst = edge + N_EDGES;

    // workspace layout (all offsets 16 B aligned)
    ushort* Xb     = (ushort*)d_ws;                       // 6,400,000 us (12.8 MB)
    ushort* Ab     = Xb + (size_t)N_NODES * D;            // 6,400,000 us
    ushort* Bb     = Ab + (size_t)N_NODES * D;            // 6,400,000 us
    float*  g      = (float*)(Bb + (size_t)N_NODES * D);  //     8,192 f
    int*   deg     = (int*)(g + (size_t)N_GRAPHS * D);    //   100,000 i
    int*   row_ptr = deg + N_NODES;                       //   100,001 i
    int*   cursor  = row_ptr + (N_NODES + 1);             //   100,000 i
    int*   csr     = cursor + N_NODES;                    // 1,200,000 i
    int*   partial = csr + N_EDGES;                       //       256 i

    dim3 blk256(256);
    dim3 grdE4((N_EDGES / 4 + 255) / 256);
    dim3 grdT((N_NODES + TILE - 1) / TILE);
    const int nodeF4 = N_NODES * D / 4;

    // ---- CSR build (by dst)
    zero_kernel<<<dim3((N_NODES / 4 + 255) / 256), blk256, 0, stream>>>((float*)deg, N_NODES / 4);
    hist_kernel<<<grdE4, blk256, 0, stream>>>(dst, deg);
    scan_partials_kernel<<<dim3(SCAN_NB), blk256, 0, stream>>>(deg, partial);
    scan_mid_kernel<<<dim3(1), blk256, 0, stream>>>(partial);
    scan_emit_kernel<<<dim3(SCAN_NB), blk256, 0, stream>>>(deg, partial, row_ptr, cursor);
    fill_kernel<<<grdE4, blk256, 0, stream>>>(src, dst, cursor, csr);

    // ---- x -> bf16; zero pooled buffer (needed by layer-3 fused pool)
    cvt_bf16_kernel<<<dim3((nodeF4 + 255) / 256), blk256, 0, stream>>>(x, Xb, nodeF4);
    zero_kernel<<<dim3((N_GRAPHS * D / 4 + 255) / 256), blk256, 0, stream>>>(g, N_GRAPHS * D / 4);

    // ---- 3 fused GraphConv layers (layer 3 pools directly into g)
    fused_layer_kernel<0><<<grdT, blk256, 0, stream>>>(Xb, row_ptr, csr, Wr1, br1, Ws1, Ab, batch, g);
    fused_layer_kernel<0><<<grdT, blk256, 0, stream>>>(Ab, row_ptr, csr, Wr2, br2, Ws2, Bb, batch, g);
    fused_layer_kernel<1><<<grdT, blk256, 0, stream>>>(Bb, row_ptr, csr, Wr3, br3, Ws3, Ab, batch, g);

    // ---- head
    head_kernel<<<dim3(N_GRAPHS), dim3(64), 0, stream>>>(g, Wfc1, bfc1, Wfc2, bfc2, (float*)d_out);
}